// Round 17
// baseline (281.755 us; speedup 1.0000x reference)
//
#include <hip/hip_runtime.h>
#include <math.h>

typedef unsigned short u16;
typedef unsigned int u32;
typedef unsigned long long u64;
typedef __attribute__((ext_vector_type(8))) short short8b;  // 8 x bf16
typedef __attribute__((ext_vector_type(4))) float f32x4;

#define N_PTS 8192
#define NTOT 16384
#define D 128
#define KNN 16
#define NCH_M 16           // minslots chunks (512 cands)
#define NCH_S 16           // select chunks (512 cands)
#define CAP 20             // survivor cap per (query, select-chunk)

__device__ __forceinline__ u16 f2bf(float x) {
    u32 u = __float_as_uint(x);
    u = (u + 0x7FFFu + ((u >> 16) & 1u)) >> 16;
    return (u16)u;
}
__device__ __forceinline__ float bf2f(u16 v) {
    return __uint_as_float(((u32)v) << 16);
}
// packed bf16 convert: lo16 = bf16(a), hi16 = bf16(b) — single VALU op
__device__ __forceinline__ u32 cvtpk(float a, float b) {
    u32 r;
    asm("v_cvt_pk_bf16_f32 %0, %1, %2" : "=v"(r) : "v"(a), "v"(b));
    return r;
}

// ---------------------------------------------------------------------------
// Kernel 1: residue-min slots, e-space. Q=2 per thread, block=64 (ONE wave),
// grid (128,16) = 2048 blocks -> 8 waves/CU (same occupancy as r14's Q=1)
// with HALF the wave count -> half the LDS-broadcast cycles. Prep folded
// into tile fill (bit-identical e-values). Validated body otherwise.
// ---------------------------------------------------------------------------
__global__ __launch_bounds__(64) void knn_minslots(const float* __restrict__ xyz,
                                                   float* __restrict__ pmins) {
    __shared__ float4 tile[512];   // 8 KB
    const int tid = threadIdx.x;
    const int qA = blockIdx.x * 128 + tid;      // [bx*128, bx*128+64)
    const int qB = qA + 64;                     // [bx*128+64, bx*128+128)
    const int cbase = (qA >> 13) * N_PTS + blockIdx.y * 512;

    const float ax = xyz[qA * 3 + 0], ay = xyz[qA * 3 + 1], az = xyz[qA * 3 + 2];
    const float bx = xyz[qB * 3 + 0], by = xyz[qB * 3 + 1], bz = xyz[qB * 3 + 2];

    for (int i = tid; i < 512; i += 64) {
        const float x = xyz[(cbase + i) * 3 + 0];
        const float y = xyz[(cbase + i) * 3 + 1];
        const float z = xyz[(cbase + i) * 3 + 2];
        tile[i] = make_float4(x, y, z, 0.5f * (x * x + y * y + z * z));
    }
    __syncthreads();

    float sA[16], sB[16];
#pragma unroll
    for (int s = 0; s < 16; ++s) { sA[s] = 1e30f; sB[s] = 1e30f; }

    for (int j0 = 0; j0 < 512; j0 += 16) {
#pragma unroll
        for (int s = 0; s < 16; ++s) {
            const float4 c = tile[j0 + s];
            sA[s] = fminf(sA[s], fmaf(-ax, c.x, fmaf(-ay, c.y, fmaf(-az, c.z, c.w))));
            sB[s] = fminf(sB[s], fmaf(-bx, c.x, fmaf(-by, c.y, fmaf(-bz, c.z, c.w))));
        }
    }
#pragma unroll
    for (int s = 0; s < 16; ++s) {
        const size_t rb = (size_t)(blockIdx.y * 16 + s) * NTOT;
        pmins[rb + qA] = sA[s];
        pmins[rb + qB] = sB[s];
    }
}

// ---------------------------------------------------------------------------
// Kernel 2: T'[g] = nextup(max_s min_chunks slots)
// ---------------------------------------------------------------------------
__global__ __launch_bounds__(256) void knn_thresh(const float* __restrict__ pmins,
                                                  float* __restrict__ thr) {
    const int g = blockIdx.x * 256 + threadIdx.x;
    float m[16];
#pragma unroll
    for (int s = 0; s < 16; ++s) m[s] = 1e30f;
    for (int ch = 0; ch < NCH_M; ++ch) {
#pragma unroll
        for (int s = 0; s < 16; ++s)
            m[s] = fminf(m[s], pmins[(size_t)(ch * 16 + s) * NTOT + g]);
    }
    float T = m[0];
#pragma unroll
    for (int s = 1; s < 16; ++s) T = fmaxf(T, m[s]);
    u32 u = __float_as_uint(T);
    u = (T >= 0.f) ? (u + 1u) : (u - 1u);
    thr[g] = __uint_as_float(u);
}

// ---------------------------------------------------------------------------
// Kernel 3: filter-and-append. Q=2 per thread, block=64 (one wave),
// grid (128,16). Append/pad semantics, layout, scan order byte-identical.
// ---------------------------------------------------------------------------
__global__ __launch_bounds__(64) void knn_select(const float* __restrict__ xyz,
                                                 const float* __restrict__ thr,
                                                 float* __restrict__ dcomp,
                                                 u16* __restrict__ jcomp) {
    __shared__ float4 tile[512];   // 8 KB
    const int tid = threadIdx.x;
    const int ch = blockIdx.y;
    const int qA = blockIdx.x * 128 + tid;
    const int qB = qA + 64;
    const int cbase = (qA >> 13) * N_PTS + ch * 512;

    const float ax = xyz[qA * 3 + 0], ay = xyz[qA * 3 + 1], az = xyz[qA * 3 + 2];
    const float bx = xyz[qB * 3 + 0], by = xyz[qB * 3 + 1], bz = xyz[qB * 3 + 2];
    const float tA = thr[qA], tB = thr[qB];

    for (int i = tid; i < 512; i += 64) {
        const float x = xyz[(cbase + i) * 3 + 0];
        const float y = xyz[(cbase + i) * 3 + 1];
        const float z = xyz[(cbase + i) * 3 + 2];
        tile[i] = make_float4(x, y, z, 0.5f * (x * x + y * y + z * z));
    }
    __syncthreads();

    int cA = 0, cB = 0;
#pragma unroll 16
    for (int j = 0; j < 512; ++j) {
        const float4 c = tile[j];
        const float eA = fmaf(-ax, c.x, fmaf(-ay, c.y, fmaf(-az, c.z, c.w)));
        const float eB = fmaf(-bx, c.x, fmaf(-by, c.y, fmaf(-bz, c.z, c.w)));
        if (eA < tA) {
            if (cA < CAP) {
                dcomp[(size_t)(ch * CAP + cA) * NTOT + qA] = eA;
                jcomp[(size_t)(ch * CAP + cA) * NTOT + qA] = (u16)j;
            }
            ++cA;
        }
        if (eB < tB) {
            if (cB < CAP) {
                dcomp[(size_t)(ch * CAP + cB) * NTOT + qB] = eB;
                jcomp[(size_t)(ch * CAP + cB) * NTOT + qB] = (u16)j;
            }
            ++cB;
        }
    }
    for (int t = min(cA, CAP); t < CAP; ++t) dcomp[(size_t)(ch * CAP + t) * NTOT + qA] = 1e30f;
    for (int t = min(cB, CAP); t < CAP; ++t) dcomp[(size_t)(ch * CAP + t) * NTOT + qB] = 1e30f;
}

// ---------------------------------------------------------------------------
// Kernel 4: merge (fixed trip, unrolled CAP batch loads). (validated)
// ---------------------------------------------------------------------------
__global__ __launch_bounds__(64) void knn_merge(const float* __restrict__ dcomp,
                                                const u16* __restrict__ jcomp,
                                                int* __restrict__ knn_out) {
    const int g = blockIdx.x * 64 + threadIdx.x;
    const int bbase = (g >> 13) * N_PTS;
    float dist[KNN];
    int idx[KNN];
#pragma unroll
    for (int s = 0; s < KNN; ++s) { dist[s] = 1e30f; idx[s] = 0; }

    for (int ch = 0; ch < NCH_S; ++ch) {
        float d[CAP];
        int jj[CAP];
#pragma unroll
        for (int t = 0; t < CAP; ++t) {
            d[t] = dcomp[(size_t)(ch * CAP + t) * NTOT + g];
            jj[t] = (int)jcomp[(size_t)(ch * CAP + t) * NTOT + g];
        }
#pragma unroll
        for (int t = 0; t < CAP; ++t) {
            if (d[t] < dist[KNN - 1]) {
                dist[KNN - 1] = d[t];
                idx[KNN - 1] = bbase + ch * 512 + jj[t];
#pragma unroll
                for (int s = KNN - 1; s > 0; --s) {
                    if (dist[s] < dist[s - 1]) {
                        const float td = dist[s]; dist[s] = dist[s - 1]; dist[s - 1] = td;
                        const int ti = idx[s]; idx[s] = idx[s - 1]; idx[s - 1] = ti;
                    }
                }
            }
        }
    }
#pragma unroll
    for (int s = 0; s < KNN; ++s) knn_out[g * KNN + s] = idx[s];
}

// ---------------------------------------------------------------------------
// Kernel 5: qkv + pack_w combined (independent work, one launch). (validated)
// ---------------------------------------------------------------------------
__global__ __launch_bounds__(256) void qkv_pack(const float* __restrict__ feat,
                                                const float* __restrict__ wq, const float* __restrict__ bq,
                                                const float* __restrict__ wk, const float* __restrict__ bk,
                                                const float* __restrict__ wv, const float* __restrict__ bv,
                                                const float* __restrict__ pw2,
                                                const float* __restrict__ aw1,
                                                const float* __restrict__ aw2,
                                                float* __restrict__ qbuf, u16* __restrict__ kb,
                                                u16* __restrict__ vb, u16* __restrict__ wp) {
    if (blockIdx.x >= 512) {
        const int i = (blockIdx.x - 512) * 256 + threadIdx.x;
        const int m = i >> 14;
        const int r = i & 16383;
        const int j = r & 7, l = (r >> 3) & 63, t = (r >> 9) & 7, q = r >> 12;
        const float* w = (m == 0) ? pw2 : (m == 1) ? aw1 : aw2;
        wp[i] = f2bf(w[(q * 32 + 8 * (l >> 4) + j) * D + t * 16 + (l & 15)]);
        return;
    }

    __shared__ float ftile[32][D];   // 16 KB
    const int r0 = blockIdx.x * 32;

    const float* src = feat + (size_t)r0 * D;
    for (int i = threadIdx.x; i < 32 * D / 4; i += 256) {
        ((float4*)&ftile[0][0])[i] = ((const float4*)src)[i];
    }
    __syncthreads();

    const int col = threadIdx.x & (D - 1);
    const int rbase = (threadIdx.x >> 7) * 16;

    float accq[16], acck[16], accv[16];
    const float bqv = bq[col], bkv = bk[col], bvv = bv[col];
#pragma unroll
    for (int r = 0; r < 16; ++r) { accq[r] = bqv; acck[r] = bkv; accv[r] = bvv; }

    for (int i = 0; i < D; i += 4) {
        const float wq0 = wq[(i + 0) * D + col], wq1 = wq[(i + 1) * D + col];
        const float wq2 = wq[(i + 2) * D + col], wq3 = wq[(i + 3) * D + col];
        const float wk0 = wk[(i + 0) * D + col], wk1 = wk[(i + 1) * D + col];
        const float wk2 = wk[(i + 2) * D + col], wk3 = wk[(i + 3) * D + col];
        const float wv0 = wv[(i + 0) * D + col], wv1 = wv[(i + 1) * D + col];
        const float wv2 = wv[(i + 2) * D + col], wv3 = wv[(i + 3) * D + col];
#pragma unroll
        for (int r = 0; r < 16; ++r) {
            const float4 f = *(const float4*)&ftile[rbase + r][i];
            accq[r] = fmaf(f.x, wq0, accq[r]); accq[r] = fmaf(f.y, wq1, accq[r]);
            accq[r] = fmaf(f.z, wq2, accq[r]); accq[r] = fmaf(f.w, wq3, accq[r]);
            acck[r] = fmaf(f.x, wk0, acck[r]); acck[r] = fmaf(f.y, wk1, acck[r]);
            acck[r] = fmaf(f.z, wk2, acck[r]); acck[r] = fmaf(f.w, wk3, acck[r]);
            accv[r] = fmaf(f.x, wv0, accv[r]); accv[r] = fmaf(f.y, wv1, accv[r]);
            accv[r] = fmaf(f.z, wv2, accv[r]); accv[r] = fmaf(f.w, wv3, accv[r]);
        }
    }
#pragma unroll
    for (int r = 0; r < 16; ++r) {
        const size_t o = (size_t)(r0 + rbase + r) * D + col;
        qbuf[o] = accq[r]; kb[o] = f2bf(acck[r]); vb[o] = f2bf(accv[r]);
    }
}

// ---------------------------------------------------------------------------
// Kernel 6: fused point transformer v8 (validated round 12/14, unchanged).
// ---------------------------------------------------------------------------
__device__ __forceinline__ void gemm_reg(const char* atile, const short8b (&wf)[4][2],
                                         const float* brow, int R, int c2, int lane,
                                         f32x4 (&acc)[4][2]) {
    const int c16 = lane & 15, grp = lane >> 4;
#pragma unroll
    for (int mt = 0; mt < 4; ++mt)
#pragma unroll
        for (int ct = 0; ct < 2; ++ct) {
            const float b = brow[c2 * 32 + ct * 16 + c16];
            acc[mt][ct] = (f32x4){b, b, b, b};
        }
#pragma unroll
    for (int q = 0; q < 4; ++q) {
        short8b af[4];
#pragma unroll
        for (int mt = 0; mt < 4; ++mt) {
            const int row = R * 64 + mt * 16 + c16;
            const int byte = (row * 256 + (q * 32 + grp * 8) * 2) ^ ((row & 7) << 4);
            af[mt] = *(const short8b*)(atile + byte);
        }
#pragma unroll
        for (int mt = 0; mt < 4; ++mt)
#pragma unroll
            for (int ct = 0; ct < 2; ++ct)
                acc[mt][ct] = __builtin_amdgcn_mfma_f32_16x16x32_bf16(af[mt], wf[q][ct], acc[mt][ct], 0, 0, 0);
    }
}

__device__ __forceinline__ void pair_store(char* atile, int rowbase, int col, bool odd,
                                           float v0, float v1, float v2, float v3) {
    const float p0 = __shfl_xor(v0, 1), p1 = __shfl_xor(v1, 1);
    const float p2 = __shfl_xor(v2, 1), p3 = __shfl_xor(v3, 1);
    const float eA = odd ? p2 : v0, oA = odd ? v2 : p0;
    const float eB = odd ? p3 : v1, oB = odd ? v3 : p1;
    const u32 wa = cvtpk(eA, oA);
    const u32 wb = cvtpk(eB, oB);
    const int cb = (col & ~1) * 2;
    const int ra = rowbase + (odd ? 2 : 0);
    const int rb = ra + 1;
    *(u32*)(atile + ((ra * 256 + cb) ^ ((ra & 7) << 4))) = wa;
    *(u32*)(atile + ((rb * 256 + cb) ^ ((rb & 7) << 4))) = wb;
}

__global__ __launch_bounds__(512, 2) void fused_v8(const float* __restrict__ xyz,
                                                   const float* __restrict__ qbuf,
                                                   const u16* __restrict__ kb,
                                                   const u16* __restrict__ vb,
                                                   const int* __restrict__ knn_in,
                                                   const u16* __restrict__ wpack,
                                                   const float* __restrict__ pw1,
                                                   const float* __restrict__ pb1,
                                                   const float* __restrict__ pb2,
                                                   const float* __restrict__ ab1,
                                                   const float* __restrict__ ab2,
                                                   float* __restrict__ out) {
    __shared__ __align__(16) char atile[32768];   // [128][128] bf16 swizzled
    __shared__ float bias[3][D];                  // pb2, ab1, ab2
    __shared__ __align__(16) float diffs[128][4];
    __shared__ int nbrs[128];

    const int tid = threadIdx.x;
    if (tid < 128) bias[0][tid] = pb2[tid];
    else if (tid < 256) bias[1][tid - 128] = ab1[tid - 128];
    else if (tid < 384) bias[2][tid - 256] = ab2[tid - 256];

    const int wid = tid >> 6, lane = tid & 63;
    const int R = wid >> 2, c2 = wid & 3;
    const int c16 = lane & 15, grp = lane >> 4;
    const bool odd = (c16 & 1) != 0;

    // XCD-aware bijective swizzle for 512 blocks
    const int pid = (blockIdx.x & 7) * 64 + (blockIdx.x >> 3);

    // P2 hoisted pos-MLP-1 weights: 4 cols per thread (loop-invariant)
    const int cb4 = (tid & 31) * 4;   // column base
    const int rblk = tid >> 5;        // row block 0..15 (8 rows each)
    float w0a[4], w1a[4], w2a[4], ba[4];
#pragma unroll
    for (int c = 0; c < 4; ++c) {
        w0a[c] = pw1[cb4 + c];
        w1a[c] = pw1[D + cb4 + c];
        w2a[c] = pw1[2 * D + cb4 + c];
        ba[c]  = pb1[cb4 + c];
    }

    short8b wf[3][4][2];
#pragma unroll
    for (int m = 0; m < 3; ++m)
#pragma unroll
        for (int q = 0; q < 4; ++q)
#pragma unroll
            for (int ct = 0; ct < 2; ++ct)
                wf[m][q][ct] = *(const short8b*)(wpack + (size_t)m * 16384 +
                                                 (size_t)((q * 8 + c2 * 2 + ct) * 64 + lane) * 8);
    __syncthreads();

    for (int g = 0; g < 4; ++g) {
        const int p0 = pid * 32 + g * 8;
        __syncthreads();

        // P1: neighbor ids + pos diffs
        if (tid < 128) {
            const int pt = p0 + (tid >> 4);
            const int nb = knn_in[pt * KNN + (tid & 15)];
            nbrs[tid] = nb;
            diffs[tid][0] = xyz[pt * 3 + 0] - xyz[nb * 3 + 0];
            diffs[tid][1] = xyz[pt * 3 + 1] - xyz[nb * 3 + 1];
            diffs[tid][2] = xyz[pt * 3 + 2] - xyz[nb * 3 + 2];
        }
        __syncthreads();

        // P2: h1 = relu(pos_diff @ pw1 + pb1) -> atile
#pragma unroll
        for (int rr = 0; rr < 8; ++rr) {
            const int row = rblk * 8 + rr;
            const float4 dv = *(const float4*)&diffs[row][0];
            float h[4];
#pragma unroll
            for (int c = 0; c < 4; ++c) {
                float t = ba[c];
                t = fmaf(dv.x, w0a[c], t);
                t = fmaf(dv.y, w1a[c], t);
                t = fmaf(dv.z, w2a[c], t);
                h[c] = fmaxf(t, 0.f);
            }
            const u32 lo = cvtpk(h[0], h[1]);
            const u32 hi = cvtpk(h[2], h[3]);
            const u64 pk = (u64)lo | ((u64)hi << 32);
            const int byte = (row * 256 + cb4 * 2) ^ ((row & 7) << 4);
            *(u64*)(atile + byte) = pk;
        }
        __syncthreads();

        // P3: delta = h1 @ pw2 + pb2
        f32x4 del[4][2];
        gemm_reg(atile, wf[0], bias[0], R, c2, lane, del);
        __syncthreads();

        // P4: attn_in = q - k_g + delta -> atile
#pragma unroll
        for (int mt = 0; mt < 4; ++mt) {
            const int pt = p0 + R * 4 + mt;
            const int rowbase = R * 64 + mt * 16 + grp * 4;
#pragma unroll
            for (int ct = 0; ct < 2; ++ct) {
                const int col = c2 * 32 + ct * 16 + c16;
                const float qv = qbuf[(size_t)pt * D + col];
                float v[4];
#pragma unroll
                for (int r = 0; r < 4; ++r) {
                    const float kg = bf2f(kb[(size_t)nbrs[rowbase + r] * D + col]);
                    v[r] = qv - kg + del[mt][ct][r];
                }
                pair_store(atile, rowbase, col, odd, v[0], v[1], v[2], v[3]);
            }
        }
        __syncthreads();

        // P5: h2 = relu(attn_in @ aw1 + ab1)
        f32x4 acc[4][2];
        gemm_reg(atile, wf[1], bias[1], R, c2, lane, acc);
        __syncthreads();

        // P6: store relu(h2) -> atile
#pragma unroll
        for (int mt = 0; mt < 4; ++mt) {
            const int rowbase = R * 64 + mt * 16 + grp * 4;
#pragma unroll
            for (int ct = 0; ct < 2; ++ct) {
                const int col = c2 * 32 + ct * 16 + c16;
                pair_store(atile, rowbase, col, odd,
                           fmaxf(acc[mt][ct][0], 0.f), fmaxf(acc[mt][ct][1], 0.f),
                           fmaxf(acc[mt][ct][2], 0.f), fmaxf(acc[mt][ct][3], 0.f));
            }
        }
        __syncthreads();

        // P7: logits = h2 @ aw2 + ab2
        gemm_reg(atile, wf[2], bias[2], R, c2, lane, acc);

        // P8: softmax + weighted sum; predicated out-write
#pragma unroll
        for (int mt = 0; mt < 4; ++mt) {
            const int pt = p0 + R * 4 + mt;
            const int rowbase = R * 64 + mt * 16 + grp * 4;
#pragma unroll
            for (int ct = 0; ct < 2; ++ct) {
                const int col = c2 * 32 + ct * 16 + c16;
                float vg[4];
#pragma unroll
                for (int r = 0; r < 4; ++r)
                    vg[r] = bf2f(vb[(size_t)nbrs[rowbase + r] * D + col]);
                float m = fmaxf(fmaxf(acc[mt][ct][0], acc[mt][ct][1]),
                                fmaxf(acc[mt][ct][2], acc[mt][ct][3]));
                m = fmaxf(m, __shfl_xor(m, 16));
                m = fmaxf(m, __shfl_xor(m, 32));
                float e[4], s = 0.f;
#pragma unroll
                for (int r = 0; r < 4; ++r) { e[r] = __expf(acc[mt][ct][r] - m); s += e[r]; }
                s += __shfl_xor(s, 16);
                s += __shfl_xor(s, 32);
                const float inv = 1.f / s;
                float o = 0.f;
#pragma unroll
                for (int r = 0; r < 4; ++r) o = fmaf(e[r] * inv, vg[r] + del[mt][ct][r], o);
                o += __shfl_xor(o, 16);
                o += __shfl_xor(o, 32);
                if (grp == mt) out[(size_t)pt * D + col] = o;
            }
        }
    }
}

// ---------------------------------------------------------------------------
extern "C" void kernel_launch(void* const* d_in, const int* in_sizes, int n_in,
                              void* d_out, int out_size, void* d_ws, size_t ws_size,
                              hipStream_t stream) {
    const float* xyz = (const float*)d_in[0];
    const float* feat = (const float*)d_in[1];
    const float* wq = (const float*)d_in[2];
    const float* bq = (const float*)d_in[3];
    const float* wk = (const float*)d_in[4];
    const float* bk = (const float*)d_in[5];
    const float* wv = (const float*)d_in[6];
    const float* bv = (const float*)d_in[7];
    const float* pw1 = (const float*)d_in[8];
    const float* pb1 = (const float*)d_in[9];
    const float* pw2 = (const float*)d_in[10];
    const float* pb2 = (const float*)d_in[11];
    const float* aw1 = (const float*)d_in[12];
    const float* ab1 = (const float*)d_in[13];
    const float* aw2 = (const float*)d_in[14];
    const float* ab2 = (const float*)d_in[15];

    float* ws = (float*)d_ws;
    // --- knn phase ---
    float* dcomp = ws;                              // 16*20*16384 = 5,242,880 f32
    float* pmins = ws;                              // overlays: 256*16384 f32
    u16* jcomp = (u16*)(ws + 5242880);              // 5,242,880 u16
    float* thr = ws + 8126464;                      // 16,384 f32
    int* knn = (int*)(ws + 8142848);                // 262,144 i32
    // --- mlp phase (overlays dcomp region, dead after merge) ---
    float* qbuf = ws;                               // 2,097,152 f32
    u16* kb = (u16*)(ws + 2097152);                 // 2,097,152 u16
    u16* vb = (u16*)(ws + 3145728);                 // 2,097,152 u16
    u16* wpack = (u16*)(ws + 4194304);              // 49,152 u16
    float* out = (float*)d_out;

    hipLaunchKernelGGL(knn_minslots, dim3(128, NCH_M), dim3(64), 0, stream, xyz, pmins);
    hipLaunchKernelGGL(knn_thresh, dim3(64), dim3(256), 0, stream, pmins, thr);
    hipLaunchKernelGGL(knn_select, dim3(128, NCH_S), dim3(64), 0, stream,
                       xyz, thr, dcomp, jcomp);
    hipLaunchKernelGGL(knn_merge, dim3(256), dim3(64), 0, stream, dcomp, jcomp, knn);
    hipLaunchKernelGGL(qkv_pack, dim3(704), dim3(256), 0, stream,
                       feat, wq, bq, wk, bk, wv, bv, pw2, aw1, aw2,
                       qbuf, kb, vb, wpack);
    hipLaunchKernelGGL(fused_v8, dim3(512), dim3(512), 0, stream,
                       xyz, qbuf, kb, vb, knn, wpack,
                       pw1, pb1, pb2, ab1, ab2, out);
}

// Round 18
// 256.772 us; speedup vs baseline: 1.0973x; 1.0973x over previous
//
#include <hip/hip_runtime.h>
#include <math.h>

typedef unsigned short u16;
typedef unsigned int u32;
typedef unsigned long long u64;
typedef __attribute__((ext_vector_type(8))) short short8b;  // 8 x bf16
typedef __attribute__((ext_vector_type(4))) float f32x4;

#define N_PTS 8192
#define NTOT 16384
#define D 128
#define KNN 16
#define NCH_M 16           // minslots chunks (512 cands)
#define NCH_S 16           // select chunks (512 cands)
#define CAP 20             // survivor cap per (query, select-chunk)

__device__ __forceinline__ u16 f2bf(float x) {
    u32 u = __float_as_uint(x);
    u = (u + 0x7FFFu + ((u >> 16) & 1u)) >> 16;
    return (u16)u;
}
__device__ __forceinline__ float bf2f(u16 v) {
    return __uint_as_float(((u32)v) << 16);
}
// packed bf16 convert: lo16 = bf16(a), hi16 = bf16(b) — single VALU op
__device__ __forceinline__ u32 cvtpk(float a, float b) {
    u32 r;
    asm("v_cvt_pk_bf16_f32 %0, %1, %2" : "=v"(r) : "v"(a), "v"(b));
    return r;
}

// ---------------------------------------------------------------------------
// Kernel 1: residue-min slots, e-space. r16 config (best validated):
// 1 query/thread, block 128 (2 waves), grid (128,16) -> 16 waves/CU.
// Occupancy is the dominant lever for these latency-bound scans (r17 lesson:
// halving waves/CU cost 25 us). Prep folded into tile fill.
// ---------------------------------------------------------------------------
__global__ __launch_bounds__(128) void knn_minslots(const float* __restrict__ xyz,
                                                    float* __restrict__ pmins) {
    __shared__ float4 tile[512];   // 8 KB
    const int tid = threadIdx.x;
    const int qA = blockIdx.x * 128 + tid;
    const int cbase = (qA >> 13) * N_PTS + blockIdx.y * 512;

    const float ax = xyz[qA * 3 + 0];
    const float ay = xyz[qA * 3 + 1];
    const float az = xyz[qA * 3 + 2];

    for (int i = tid; i < 512; i += 128) {
        const float x = xyz[(cbase + i) * 3 + 0];
        const float y = xyz[(cbase + i) * 3 + 1];
        const float z = xyz[(cbase + i) * 3 + 2];
        tile[i] = make_float4(x, y, z, 0.5f * (x * x + y * y + z * z));
    }
    __syncthreads();

    float sA[16];
#pragma unroll
    for (int s = 0; s < 16; ++s) sA[s] = 1e30f;

    for (int j0 = 0; j0 < 512; j0 += 16) {
#pragma unroll
        for (int s = 0; s < 16; ++s) {
            const float4 c = tile[j0 + s];
            sA[s] = fminf(sA[s], fmaf(-ax, c.x, fmaf(-ay, c.y, fmaf(-az, c.z, c.w))));
        }
    }
#pragma unroll
    for (int s = 0; s < 16; ++s)
        pmins[(size_t)(blockIdx.y * 16 + s) * NTOT + qA] = sA[s];
}

// ---------------------------------------------------------------------------
// Kernel 2: T'[g] = nextup(max_s min_chunks slots)
// ---------------------------------------------------------------------------
__global__ __launch_bounds__(256) void knn_thresh(const float* __restrict__ pmins,
                                                  float* __restrict__ thr) {
    const int g = blockIdx.x * 256 + threadIdx.x;
    float m[16];
#pragma unroll
    for (int s = 0; s < 16; ++s) m[s] = 1e30f;
    for (int ch = 0; ch < NCH_M; ++ch) {
#pragma unroll
        for (int s = 0; s < 16; ++s)
            m[s] = fminf(m[s], pmins[(size_t)(ch * 16 + s) * NTOT + g]);
    }
    float T = m[0];
#pragma unroll
    for (int s = 1; s < 16; ++s) T = fmaxf(T, m[s]);
    u32 u = __float_as_uint(T);
    u = (T >= 0.f) ? (u + 1u) : (u - 1u);
    thr[g] = __uint_as_float(u);
}

// ---------------------------------------------------------------------------
// Kernel 3: filter-and-append. r16 config: 1 query/thread, block 128,
// grid (128,16) -> 16 waves/CU. Validated body.
// ---------------------------------------------------------------------------
__global__ __launch_bounds__(128) void knn_select(const float* __restrict__ xyz,
                                                  const float* __restrict__ thr,
                                                  float* __restrict__ dcomp,
                                                  u16* __restrict__ jcomp) {
    __shared__ float4 tile[512];   // 8 KB
    const int tid = threadIdx.x;
    const int ch = blockIdx.y;
    const int qA = blockIdx.x * 128 + tid;
    const int cbase = (qA >> 13) * N_PTS + ch * 512;

    const float ax = xyz[qA * 3 + 0];
    const float ay = xyz[qA * 3 + 1];
    const float az = xyz[qA * 3 + 2];
    const float tA = thr[qA];

    for (int i = tid; i < 512; i += 128) {
        const float x = xyz[(cbase + i) * 3 + 0];
        const float y = xyz[(cbase + i) * 3 + 1];
        const float z = xyz[(cbase + i) * 3 + 2];
        tile[i] = make_float4(x, y, z, 0.5f * (x * x + y * y + z * z));
    }
    __syncthreads();

    int cA = 0;
#pragma unroll 16
    for (int j = 0; j < 512; ++j) {
        const float4 c = tile[j];
        const float eA = fmaf(-ax, c.x, fmaf(-ay, c.y, fmaf(-az, c.z, c.w)));
        if (eA < tA) {
            if (cA < CAP) {
                dcomp[(size_t)(ch * CAP + cA) * NTOT + qA] = eA;
                jcomp[(size_t)(ch * CAP + cA) * NTOT + qA] = (u16)j;
            }
            ++cA;
        }
    }
    for (int t = min(cA, CAP); t < CAP; ++t) dcomp[(size_t)(ch * CAP + t) * NTOT + qA] = 1e30f;
}

// ---------------------------------------------------------------------------
// Kernel 4: merge (fixed trip, unrolled CAP batch loads). (validated)
// ---------------------------------------------------------------------------
__global__ __launch_bounds__(64) void knn_merge(const float* __restrict__ dcomp,
                                                const u16* __restrict__ jcomp,
                                                int* __restrict__ knn_out) {
    const int g = blockIdx.x * 64 + threadIdx.x;
    const int bbase = (g >> 13) * N_PTS;
    float dist[KNN];
    int idx[KNN];
#pragma unroll
    for (int s = 0; s < KNN; ++s) { dist[s] = 1e30f; idx[s] = 0; }

    for (int ch = 0; ch < NCH_S; ++ch) {
        float d[CAP];
        int jj[CAP];
#pragma unroll
        for (int t = 0; t < CAP; ++t) {
            d[t] = dcomp[(size_t)(ch * CAP + t) * NTOT + g];
            jj[t] = (int)jcomp[(size_t)(ch * CAP + t) * NTOT + g];
        }
#pragma unroll
        for (int t = 0; t < CAP; ++t) {
            if (d[t] < dist[KNN - 1]) {
                dist[KNN - 1] = d[t];
                idx[KNN - 1] = bbase + ch * 512 + jj[t];
#pragma unroll
                for (int s = KNN - 1; s > 0; --s) {
                    if (dist[s] < dist[s - 1]) {
                        const float td = dist[s]; dist[s] = dist[s - 1]; dist[s - 1] = td;
                        const int ti = idx[s]; idx[s] = idx[s - 1]; idx[s - 1] = ti;
                    }
                }
            }
        }
    }
#pragma unroll
    for (int s = 0; s < KNN; ++s) knn_out[g * KNN + s] = idx[s];
}

// ---------------------------------------------------------------------------
// Kernel 5: qkv + pack_w combined (independent work, one launch).
// Blocks 0..511: q/k/v projections, 32 rows each (validated body).
// Blocks 512..703: pack pw2/aw1/aw2 into bf16 B-fragment order (validated).
// ---------------------------------------------------------------------------
__global__ __launch_bounds__(256) void qkv_pack(const float* __restrict__ feat,
                                                const float* __restrict__ wq, const float* __restrict__ bq,
                                                const float* __restrict__ wk, const float* __restrict__ bk,
                                                const float* __restrict__ wv, const float* __restrict__ bv,
                                                const float* __restrict__ pw2,
                                                const float* __restrict__ aw1,
                                                const float* __restrict__ aw2,
                                                float* __restrict__ qbuf, u16* __restrict__ kb,
                                                u16* __restrict__ vb, u16* __restrict__ wp) {
    if (blockIdx.x >= 512) {
        const int i = (blockIdx.x - 512) * 256 + threadIdx.x;
        const int m = i >> 14;
        const int r = i & 16383;
        const int j = r & 7, l = (r >> 3) & 63, t = (r >> 9) & 7, q = r >> 12;
        const float* w = (m == 0) ? pw2 : (m == 1) ? aw1 : aw2;
        wp[i] = f2bf(w[(q * 32 + 8 * (l >> 4) + j) * D + t * 16 + (l & 15)]);
        return;
    }

    __shared__ float ftile[32][D];   // 16 KB
    const int r0 = blockIdx.x * 32;

    const float* src = feat + (size_t)r0 * D;
    for (int i = threadIdx.x; i < 32 * D / 4; i += 256) {
        ((float4*)&ftile[0][0])[i] = ((const float4*)src)[i];
    }
    __syncthreads();

    const int col = threadIdx.x & (D - 1);
    const int rbase = (threadIdx.x >> 7) * 16;

    float accq[16], acck[16], accv[16];
    const float bqv = bq[col], bkv = bk[col], bvv = bv[col];
#pragma unroll
    for (int r = 0; r < 16; ++r) { accq[r] = bqv; acck[r] = bkv; accv[r] = bvv; }

    for (int i = 0; i < D; i += 4) {
        const float wq0 = wq[(i + 0) * D + col], wq1 = wq[(i + 1) * D + col];
        const float wq2 = wq[(i + 2) * D + col], wq3 = wq[(i + 3) * D + col];
        const float wk0 = wk[(i + 0) * D + col], wk1 = wk[(i + 1) * D + col];
        const float wk2 = wk[(i + 2) * D + col], wk3 = wk[(i + 3) * D + col];
        const float wv0 = wv[(i + 0) * D + col], wv1 = wv[(i + 1) * D + col];
        const float wv2 = wv[(i + 2) * D + col], wv3 = wv[(i + 3) * D + col];
#pragma unroll
        for (int r = 0; r < 16; ++r) {
            const float4 f = *(const float4*)&ftile[rbase + r][i];
            accq[r] = fmaf(f.x, wq0, accq[r]); accq[r] = fmaf(f.y, wq1, accq[r]);
            accq[r] = fmaf(f.z, wq2, accq[r]); accq[r] = fmaf(f.w, wq3, accq[r]);
            acck[r] = fmaf(f.x, wk0, acck[r]); acck[r] = fmaf(f.y, wk1, acck[r]);
            acck[r] = fmaf(f.z, wk2, acck[r]); acck[r] = fmaf(f.w, wk3, acck[r]);
            accv[r] = fmaf(f.x, wv0, accv[r]); accv[r] = fmaf(f.y, wv1, accv[r]);
            accv[r] = fmaf(f.z, wv2, accv[r]); accv[r] = fmaf(f.w, wv3, accv[r]);
        }
    }
#pragma unroll
    for (int r = 0; r < 16; ++r) {
        const size_t o = (size_t)(r0 + rbase + r) * D + col;
        qbuf[o] = accq[r]; kb[o] = f2bf(acck[r]); vb[o] = f2bf(accv[r]);
    }
}

// ---------------------------------------------------------------------------
// Kernel 6: fused point transformer v8 (validated round 12/14, unchanged).
// ---------------------------------------------------------------------------
__device__ __forceinline__ void gemm_reg(const char* atile, const short8b (&wf)[4][2],
                                         const float* brow, int R, int c2, int lane,
                                         f32x4 (&acc)[4][2]) {
    const int c16 = lane & 15, grp = lane >> 4;
#pragma unroll
    for (int mt = 0; mt < 4; ++mt)
#pragma unroll
        for (int ct = 0; ct < 2; ++ct) {
            const float b = brow[c2 * 32 + ct * 16 + c16];
            acc[mt][ct] = (f32x4){b, b, b, b};
        }
#pragma unroll
    for (int q = 0; q < 4; ++q) {
        short8b af[4];
#pragma unroll
        for (int mt = 0; mt < 4; ++mt) {
            const int row = R * 64 + mt * 16 + c16;
            const int byte = (row * 256 + (q * 32 + grp * 8) * 2) ^ ((row & 7) << 4);
            af[mt] = *(const short8b*)(atile + byte);
        }
#pragma unroll
        for (int mt = 0; mt < 4; ++mt)
#pragma unroll
            for (int ct = 0; ct < 2; ++ct)
                acc[mt][ct] = __builtin_amdgcn_mfma_f32_16x16x32_bf16(af[mt], wf[q][ct], acc[mt][ct], 0, 0, 0);
    }
}

__device__ __forceinline__ void pair_store(char* atile, int rowbase, int col, bool odd,
                                           float v0, float v1, float v2, float v3) {
    const float p0 = __shfl_xor(v0, 1), p1 = __shfl_xor(v1, 1);
    const float p2 = __shfl_xor(v2, 1), p3 = __shfl_xor(v3, 1);
    const float eA = odd ? p2 : v0, oA = odd ? v2 : p0;
    const float eB = odd ? p3 : v1, oB = odd ? v3 : p1;
    const u32 wa = cvtpk(eA, oA);
    const u32 wb = cvtpk(eB, oB);
    const int cb = (col & ~1) * 2;
    const int ra = rowbase + (odd ? 2 : 0);
    const int rb = ra + 1;
    *(u32*)(atile + ((ra * 256 + cb) ^ ((ra & 7) << 4))) = wa;
    *(u32*)(atile + ((rb * 256 + cb) ^ ((rb & 7) << 4))) = wb;
}

__global__ __launch_bounds__(512, 2) void fused_v8(const float* __restrict__ xyz,
                                                   const float* __restrict__ qbuf,
                                                   const u16* __restrict__ kb,
                                                   const u16* __restrict__ vb,
                                                   const int* __restrict__ knn_in,
                                                   const u16* __restrict__ wpack,
                                                   const float* __restrict__ pw1,
                                                   const float* __restrict__ pb1,
                                                   const float* __restrict__ pb2,
                                                   const float* __restrict__ ab1,
                                                   const float* __restrict__ ab2,
                                                   float* __restrict__ out) {
    __shared__ __align__(16) char atile[32768];   // [128][128] bf16 swizzled
    __shared__ float bias[3][D];                  // pb2, ab1, ab2
    __shared__ __align__(16) float diffs[128][4];
    __shared__ int nbrs[128];

    const int tid = threadIdx.x;
    if (tid < 128) bias[0][tid] = pb2[tid];
    else if (tid < 256) bias[1][tid - 128] = ab1[tid - 128];
    else if (tid < 384) bias[2][tid - 256] = ab2[tid - 256];

    const int wid = tid >> 6, lane = tid & 63;
    const int R = wid >> 2, c2 = wid & 3;
    const int c16 = lane & 15, grp = lane >> 4;
    const bool odd = (c16 & 1) != 0;

    // XCD-aware bijective swizzle for 512 blocks
    const int pid = (blockIdx.x & 7) * 64 + (blockIdx.x >> 3);

    // P2 hoisted pos-MLP-1 weights: 4 cols per thread (loop-invariant)
    const int cb4 = (tid & 31) * 4;   // column base
    const int rblk = tid >> 5;        // row block 0..15 (8 rows each)
    float w0a[4], w1a[4], w2a[4], ba[4];
#pragma unroll
    for (int c = 0; c < 4; ++c) {
        w0a[c] = pw1[cb4 + c];
        w1a[c] = pw1[D + cb4 + c];
        w2a[c] = pw1[2 * D + cb4 + c];
        ba[c]  = pb1[cb4 + c];
    }

    short8b wf[3][4][2];
#pragma unroll
    for (int m = 0; m < 3; ++m)
#pragma unroll
        for (int q = 0; q < 4; ++q)
#pragma unroll
            for (int ct = 0; ct < 2; ++ct)
                wf[m][q][ct] = *(const short8b*)(wpack + (size_t)m * 16384 +
                                                 (size_t)((q * 8 + c2 * 2 + ct) * 64 + lane) * 8);
    __syncthreads();

    for (int g = 0; g < 4; ++g) {
        const int p0 = pid * 32 + g * 8;
        __syncthreads();

        // P1: neighbor ids + pos diffs
        if (tid < 128) {
            const int pt = p0 + (tid >> 4);
            const int nb = knn_in[pt * KNN + (tid & 15)];
            nbrs[tid] = nb;
            diffs[tid][0] = xyz[pt * 3 + 0] - xyz[nb * 3 + 0];
            diffs[tid][1] = xyz[pt * 3 + 1] - xyz[nb * 3 + 1];
            diffs[tid][2] = xyz[pt * 3 + 2] - xyz[nb * 3 + 2];
        }
        __syncthreads();

        // P2: h1 = relu(pos_diff @ pw1 + pb1) -> atile
#pragma unroll
        for (int rr = 0; rr < 8; ++rr) {
            const int row = rblk * 8 + rr;
            const float4 dv = *(const float4*)&diffs[row][0];
            float h[4];
#pragma unroll
            for (int c = 0; c < 4; ++c) {
                float t = ba[c];
                t = fmaf(dv.x, w0a[c], t);
                t = fmaf(dv.y, w1a[c], t);
                t = fmaf(dv.z, w2a[c], t);
                h[c] = fmaxf(t, 0.f);
            }
            const u32 lo = cvtpk(h[0], h[1]);
            const u32 hi = cvtpk(h[2], h[3]);
            const u64 pk = (u64)lo | ((u64)hi << 32);
            const int byte = (row * 256 + cb4 * 2) ^ ((row & 7) << 4);
            *(u64*)(atile + byte) = pk;
        }
        __syncthreads();

        // P3: delta = h1 @ pw2 + pb2
        f32x4 del[4][2];
        gemm_reg(atile, wf[0], bias[0], R, c2, lane, del);
        __syncthreads();

        // P4: attn_in = q - k_g + delta -> atile
#pragma unroll
        for (int mt = 0; mt < 4; ++mt) {
            const int pt = p0 + R * 4 + mt;
            const int rowbase = R * 64 + mt * 16 + grp * 4;
#pragma unroll
            for (int ct = 0; ct < 2; ++ct) {
                const int col = c2 * 32 + ct * 16 + c16;
                const float qv = qbuf[(size_t)pt * D + col];
                float v[4];
#pragma unroll
                for (int r = 0; r < 4; ++r) {
                    const float kg = bf2f(kb[(size_t)nbrs[rowbase + r] * D + col]);
                    v[r] = qv - kg + del[mt][ct][r];
                }
                pair_store(atile, rowbase, col, odd, v[0], v[1], v[2], v[3]);
            }
        }
        __syncthreads();

        // P5: h2 = relu(attn_in @ aw1 + ab1)
        f32x4 acc[4][2];
        gemm_reg(atile, wf[1], bias[1], R, c2, lane, acc);
        __syncthreads();

        // P6: store relu(h2) -> atile
#pragma unroll
        for (int mt = 0; mt < 4; ++mt) {
            const int rowbase = R * 64 + mt * 16 + grp * 4;
#pragma unroll
            for (int ct = 0; ct < 2; ++ct) {
                const int col = c2 * 32 + ct * 16 + c16;
                pair_store(atile, rowbase, col, odd,
                           fmaxf(acc[mt][ct][0], 0.f), fmaxf(acc[mt][ct][1], 0.f),
                           fmaxf(acc[mt][ct][2], 0.f), fmaxf(acc[mt][ct][3], 0.f));
            }
        }
        __syncthreads();

        // P7: logits = h2 @ aw2 + ab2
        gemm_reg(atile, wf[2], bias[2], R, c2, lane, acc);

        // P8: softmax + weighted sum; predicated out-write
#pragma unroll
        for (int mt = 0; mt < 4; ++mt) {
            const int pt = p0 + R * 4 + mt;
            const int rowbase = R * 64 + mt * 16 + grp * 4;
#pragma unroll
            for (int ct = 0; ct < 2; ++ct) {
                const int col = c2 * 32 + ct * 16 + c16;
                float vg[4];
#pragma unroll
                for (int r = 0; r < 4; ++r)
                    vg[r] = bf2f(vb[(size_t)nbrs[rowbase + r] * D + col]);
                float m = fmaxf(fmaxf(acc[mt][ct][0], acc[mt][ct][1]),
                                fmaxf(acc[mt][ct][2], acc[mt][ct][3]));
                m = fmaxf(m, __shfl_xor(m, 16));
                m = fmaxf(m, __shfl_xor(m, 32));
                float e[4], s = 0.f;
#pragma unroll
                for (int r = 0; r < 4; ++r) { e[r] = __expf(acc[mt][ct][r] - m); s += e[r]; }
                s += __shfl_xor(s, 16);
                s += __shfl_xor(s, 32);
                const float inv = 1.f / s;
                float o = 0.f;
#pragma unroll
                for (int r = 0; r < 4; ++r) o = fmaf(e[r] * inv, vg[r] + del[mt][ct][r], o);
                o += __shfl_xor(o, 16);
                o += __shfl_xor(o, 32);
                if (grp == mt) out[(size_t)pt * D + col] = o;
            }
        }
    }
}

// ---------------------------------------------------------------------------
extern "C" void kernel_launch(void* const* d_in, const int* in_sizes, int n_in,
                              void* d_out, int out_size, void* d_ws, size_t ws_size,
                              hipStream_t stream) {
    const float* xyz = (const float*)d_in[0];
    const float* feat = (const float*)d_in[1];
    const float* wq = (const float*)d_in[2];
    const float* bq = (const float*)d_in[3];
    const float* wk = (const float*)d_in[4];
    const float* bk = (const float*)d_in[5];
    const float* wv = (const float*)d_in[6];
    const float* bv = (const float*)d_in[7];
    const float* pw1 = (const float*)d_in[8];
    const float* pb1 = (const float*)d_in[9];
    const float* pw2 = (const float*)d_in[10];
    const float* pb2 = (const float*)d_in[11];
    const float* aw1 = (const float*)d_in[12];
    const float* ab1 = (const float*)d_in[13];
    const float* aw2 = (const float*)d_in[14];
    const float* ab2 = (const float*)d_in[15];

    float* ws = (float*)d_ws;
    // --- knn phase ---
    float* dcomp = ws;                              // 16*20*16384 = 5,242,880 f32
    float* pmins = ws;                              // overlays: 256*16384 f32
    u16* jcomp = (u16*)(ws + 5242880);              // 5,242,880 u16
    float* thr = ws + 8126464;                      // 16,384 f32
    int* knn = (int*)(ws + 8142848);                // 262,144 i32
    // --- mlp phase (overlays dcomp region, dead after merge) ---
    float* qbuf = ws;                               // 2,097,152 f32
    u16* kb = (u16*)(ws + 2097152);                 // 2,097,152 u16
    u16* vb = (u16*)(ws + 3145728);                 // 2,097,152 u16
    u16* wpack = (u16*)(ws + 4194304);              // 49,152 u16
    float* out = (float*)d_out;

    hipLaunchKernelGGL(knn_minslots, dim3(128, NCH_M), dim3(128), 0, stream, xyz, pmins);
    hipLaunchKernelGGL(knn_thresh, dim3(64), dim3(256), 0, stream, pmins, thr);
    hipLaunchKernelGGL(knn_select, dim3(128, NCH_S), dim3(128), 0, stream,
                       xyz, thr, dcomp, jcomp);
    hipLaunchKernelGGL(knn_merge, dim3(256), dim3(64), 0, stream, dcomp, jcomp, knn);
    hipLaunchKernelGGL(qkv_pack, dim3(704), dim3(256), 0, stream,
                       feat, wq, bq, wk, bk, wv, bv, pw2, aw1, aw2,
                       qbuf, kb, vb, wpack);
    hipLaunchKernelGGL(fused_v8, dim3(512), dim3(512), 0, stream,
                       xyz, qbuf, kb, vb, knn, wpack,
                       pw1, pb1, pb2, ab1, ab2, out);
}

// Round 20
// 255.759 us; speedup vs baseline: 1.1016x; 1.0040x over previous
//
#include <hip/hip_runtime.h>
#include <math.h>

typedef unsigned short u16;
typedef unsigned int u32;
typedef unsigned long long u64;
typedef __attribute__((ext_vector_type(8))) short short8b;  // 8 x bf16
typedef __attribute__((ext_vector_type(4))) float f32x4;

#define N_PTS 8192
#define NTOT 16384
#define D 128
#define KNN 16
#define NCH_M 16           // minslots chunks (512 cands)
#define NCH_S 16           // select chunks (512 cands)
#define CAP 20             // survivor cap per (query, select-chunk)

__device__ __forceinline__ u16 f2bf(float x) {
    u32 u = __float_as_uint(x);
    u = (u + 0x7FFFu + ((u >> 16) & 1u)) >> 16;
    return (u16)u;
}
__device__ __forceinline__ float bf2f(u16 v) {
    return __uint_as_float(((u32)v) << 16);
}
// packed bf16 convert: lo16 = bf16(a), hi16 = bf16(b) — single VALU op
__device__ __forceinline__ u32 cvtpk(float a, float b) {
    u32 r;
    asm("v_cvt_pk_bf16_f32 %0, %1, %2" : "=v"(r) : "v"(a), "v"(b));
    return r;
}

// ---------------------------------------------------------------------------
// Kernel 1: residue-min slots, e-space, FULL 8192-candidate scan (r19's
// 2048-sample variant FAILED: sampled threshold lands at population rank
// ~200+ -> ~13 survivors/chunk -> CAP overflow drops true neighbors).
// r16/r18 config: 1 query/thread, block 128, grid (128,16) -> 16 waves/CU.
// ---------------------------------------------------------------------------
__global__ __launch_bounds__(128) void knn_minslots(const float* __restrict__ xyz,
                                                    float* __restrict__ pmins) {
    __shared__ float4 tile[512];   // 8 KB
    const int tid = threadIdx.x;
    const int qA = blockIdx.x * 128 + tid;
    const int cbase = (qA >> 13) * N_PTS + blockIdx.y * 512;

    const float ax = xyz[qA * 3 + 0];
    const float ay = xyz[qA * 3 + 1];
    const float az = xyz[qA * 3 + 2];

    for (int i = tid; i < 512; i += 128) {
        const float x = xyz[(cbase + i) * 3 + 0];
        const float y = xyz[(cbase + i) * 3 + 1];
        const float z = xyz[(cbase + i) * 3 + 2];
        tile[i] = make_float4(x, y, z, 0.5f * (x * x + y * y + z * z));
    }
    __syncthreads();

    float sA[16];
#pragma unroll
    for (int s = 0; s < 16; ++s) sA[s] = 1e30f;

    for (int j0 = 0; j0 < 512; j0 += 16) {
#pragma unroll
        for (int s = 0; s < 16; ++s) {
            const float4 c = tile[j0 + s];
            sA[s] = fminf(sA[s], fmaf(-ax, c.x, fmaf(-ay, c.y, fmaf(-az, c.z, c.w))));
        }
    }
#pragma unroll
    for (int s = 0; s < 16; ++s)
        pmins[(size_t)(blockIdx.y * 16 + s) * NTOT + qA] = sA[s];
}

// ---------------------------------------------------------------------------
// Kernel 2: T'[g] = nextup(max_s min_chunks slots)
// ---------------------------------------------------------------------------
__global__ __launch_bounds__(256) void knn_thresh(const float* __restrict__ pmins,
                                                  float* __restrict__ thr) {
    const int g = blockIdx.x * 256 + threadIdx.x;
    float m[16];
#pragma unroll
    for (int s = 0; s < 16; ++s) m[s] = 1e30f;
    for (int ch = 0; ch < NCH_M; ++ch) {
#pragma unroll
        for (int s = 0; s < 16; ++s)
            m[s] = fminf(m[s], pmins[(size_t)(ch * 16 + s) * NTOT + g]);
    }
    float T = m[0];
#pragma unroll
    for (int s = 1; s < 16; ++s) T = fmaxf(T, m[s]);
    u32 u = __float_as_uint(T);
    u = (T >= 0.f) ? (u + 1u) : (u - 1u);
    thr[g] = __uint_as_float(u);
}

// ---------------------------------------------------------------------------
// Kernel 3: filter-and-append. r16/r18 config: 1 query/thread, block 128,
// grid (128,16) -> 16 waves/CU. Validated body.
// ---------------------------------------------------------------------------
__global__ __launch_bounds__(128) void knn_select(const float* __restrict__ xyz,
                                                  const float* __restrict__ thr,
                                                  float* __restrict__ dcomp,
                                                  u16* __restrict__ jcomp) {
    __shared__ float4 tile[512];   // 8 KB
    const int tid = threadIdx.x;
    const int ch = blockIdx.y;
    const int qA = blockIdx.x * 128 + tid;
    const int cbase = (qA >> 13) * N_PTS + ch * 512;

    const float ax = xyz[qA * 3 + 0];
    const float ay = xyz[qA * 3 + 1];
    const float az = xyz[qA * 3 + 2];
    const float tA = thr[qA];

    for (int i = tid; i < 512; i += 128) {
        const float x = xyz[(cbase + i) * 3 + 0];
        const float y = xyz[(cbase + i) * 3 + 1];
        const float z = xyz[(cbase + i) * 3 + 2];
        tile[i] = make_float4(x, y, z, 0.5f * (x * x + y * y + z * z));
    }
    __syncthreads();

    int cA = 0;
#pragma unroll 16
    for (int j = 0; j < 512; ++j) {
        const float4 c = tile[j];
        const float eA = fmaf(-ax, c.x, fmaf(-ay, c.y, fmaf(-az, c.z, c.w)));
        if (eA < tA) {
            if (cA < CAP) {
                dcomp[(size_t)(ch * CAP + cA) * NTOT + qA] = eA;
                jcomp[(size_t)(ch * CAP + cA) * NTOT + qA] = (u16)j;
            }
            ++cA;
        }
    }
    for (int t = min(cA, CAP); t < CAP; ++t) dcomp[(size_t)(ch * CAP + t) * NTOT + qA] = 1e30f;
}

// ---------------------------------------------------------------------------
// Kernel 4: merge (fixed trip, unrolled CAP batch loads). (validated)
// ---------------------------------------------------------------------------
__global__ __launch_bounds__(64) void knn_merge(const float* __restrict__ dcomp,
                                                const u16* __restrict__ jcomp,
                                                int* __restrict__ knn_out) {
    const int g = blockIdx.x * 64 + threadIdx.x;
    const int bbase = (g >> 13) * N_PTS;
    float dist[KNN];
    int idx[KNN];
#pragma unroll
    for (int s = 0; s < KNN; ++s) { dist[s] = 1e30f; idx[s] = 0; }

    for (int ch = 0; ch < NCH_S; ++ch) {
        float d[CAP];
        int jj[CAP];
#pragma unroll
        for (int t = 0; t < CAP; ++t) {
            d[t] = dcomp[(size_t)(ch * CAP + t) * NTOT + g];
            jj[t] = (int)jcomp[(size_t)(ch * CAP + t) * NTOT + g];
        }
#pragma unroll
        for (int t = 0; t < CAP; ++t) {
            if (d[t] < dist[KNN - 1]) {
                dist[KNN - 1] = d[t];
                idx[KNN - 1] = bbase + ch * 512 + jj[t];
#pragma unroll
                for (int s = KNN - 1; s > 0; --s) {
                    if (dist[s] < dist[s - 1]) {
                        const float td = dist[s]; dist[s] = dist[s - 1]; dist[s - 1] = td;
                        const int ti = idx[s]; idx[s] = idx[s - 1]; idx[s - 1] = ti;
                    }
                }
            }
        }
    }
#pragma unroll
    for (int s = 0; s < KNN; ++s) knn_out[g * KNN + s] = idx[s];
}

// ---------------------------------------------------------------------------
// Kernel 5: qkv + pack_w combined (independent work, one launch).
// Blocks 0..511: q/k/v projections, 32 rows each (validated body).
// Blocks 512..703: pack pw2/aw1/aw2 into bf16 B-fragment order (validated).
// ---------------------------------------------------------------------------
__global__ __launch_bounds__(256) void qkv_pack(const float* __restrict__ feat,
                                                const float* __restrict__ wq, const float* __restrict__ bq,
                                                const float* __restrict__ wk, const float* __restrict__ bk,
                                                const float* __restrict__ wv, const float* __restrict__ bv,
                                                const float* __restrict__ pw2,
                                                const float* __restrict__ aw1,
                                                const float* __restrict__ aw2,
                                                float* __restrict__ qbuf, u16* __restrict__ kb,
                                                u16* __restrict__ vb, u16* __restrict__ wp) {
    if (blockIdx.x >= 512) {
        const int i = (blockIdx.x - 512) * 256 + threadIdx.x;
        const int m = i >> 14;
        const int r = i & 16383;
        const int j = r & 7, l = (r >> 3) & 63, t = (r >> 9) & 7, q = r >> 12;
        const float* w = (m == 0) ? pw2 : (m == 1) ? aw1 : aw2;
        wp[i] = f2bf(w[(q * 32 + 8 * (l >> 4) + j) * D + t * 16 + (l & 15)]);
        return;
    }

    __shared__ float ftile[32][D];   // 16 KB
    const int r0 = blockIdx.x * 32;

    const float* src = feat + (size_t)r0 * D;
    for (int i = threadIdx.x; i < 32 * D / 4; i += 256) {
        ((float4*)&ftile[0][0])[i] = ((const float4*)src)[i];
    }
    __syncthreads();

    const int col = threadIdx.x & (D - 1);
    const int rbase = (threadIdx.x >> 7) * 16;

    float accq[16], acck[16], accv[16];
    const float bqv = bq[col], bkv = bk[col], bvv = bv[col];
#pragma unroll
    for (int r = 0; r < 16; ++r) { accq[r] = bqv; acck[r] = bkv; accv[r] = bvv; }

    for (int i = 0; i < D; i += 4) {
        const float wq0 = wq[(i + 0) * D + col], wq1 = wq[(i + 1) * D + col];
        const float wq2 = wq[(i + 2) * D + col], wq3 = wq[(i + 3) * D + col];
        const float wk0 = wk[(i + 0) * D + col], wk1 = wk[(i + 1) * D + col];
        const float wk2 = wk[(i + 2) * D + col], wk3 = wk[(i + 3) * D + col];
        const float wv0 = wv[(i + 0) * D + col], wv1 = wv[(i + 1) * D + col];
        const float wv2 = wv[(i + 2) * D + col], wv3 = wv[(i + 3) * D + col];
#pragma unroll
        for (int r = 0; r < 16; ++r) {
            const float4 f = *(const float4*)&ftile[rbase + r][i];
            accq[r] = fmaf(f.x, wq0, accq[r]); accq[r] = fmaf(f.y, wq1, accq[r]);
            accq[r] = fmaf(f.z, wq2, accq[r]); accq[r] = fmaf(f.w, wq3, accq[r]);
            acck[r] = fmaf(f.x, wk0, acck[r]); acck[r] = fmaf(f.y, wk1, acck[r]);
            acck[r] = fmaf(f.z, wk2, acck[r]); acck[r] = fmaf(f.w, wk3, acck[r]);
            accv[r] = fmaf(f.x, wv0, accv[r]); accv[r] = fmaf(f.y, wv1, accv[r]);
            accv[r] = fmaf(f.z, wv2, accv[r]); accv[r] = fmaf(f.w, wv3, accv[r]);
        }
    }
#pragma unroll
    for (int r = 0; r < 16; ++r) {
        const size_t o = (size_t)(r0 + rbase + r) * D + col;
        qbuf[o] = accq[r]; kb[o] = f2bf(acck[r]); vb[o] = f2bf(accv[r]);
    }
}

// ---------------------------------------------------------------------------
// Kernel 6: fused point transformer v8 (validated round 12/14, unchanged).
// ---------------------------------------------------------------------------
__device__ __forceinline__ void gemm_reg(const char* atile, const short8b (&wf)[4][2],
                                         const float* brow, int R, int c2, int lane,
                                         f32x4 (&acc)[4][2]) {
    const int c16 = lane & 15, grp = lane >> 4;
#pragma unroll
    for (int mt = 0; mt < 4; ++mt)
#pragma unroll
        for (int ct = 0; ct < 2; ++ct) {
            const float b = brow[c2 * 32 + ct * 16 + c16];
            acc[mt][ct] = (f32x4){b, b, b, b};
        }
#pragma unroll
    for (int q = 0; q < 4; ++q) {
        short8b af[4];
#pragma unroll
        for (int mt = 0; mt < 4; ++mt) {
            const int row = R * 64 + mt * 16 + c16;
            const int byte = (row * 256 + (q * 32 + grp * 8) * 2) ^ ((row & 7) << 4);
            af[mt] = *(const short8b*)(atile + byte);
        }
#pragma unroll
        for (int mt = 0; mt < 4; ++mt)
#pragma unroll
            for (int ct = 0; ct < 2; ++ct)
                acc[mt][ct] = __builtin_amdgcn_mfma_f32_16x16x32_bf16(af[mt], wf[q][ct], acc[mt][ct], 0, 0, 0);
    }
}

__device__ __forceinline__ void pair_store(char* atile, int rowbase, int col, bool odd,
                                           float v0, float v1, float v2, float v3) {
    const float p0 = __shfl_xor(v0, 1), p1 = __shfl_xor(v1, 1);
    const float p2 = __shfl_xor(v2, 1), p3 = __shfl_xor(v3, 1);
    const float eA = odd ? p2 : v0, oA = odd ? v2 : p0;
    const float eB = odd ? p3 : v1, oB = odd ? v3 : p1;
    const u32 wa = cvtpk(eA, oA);
    const u32 wb = cvtpk(eB, oB);
    const int cb = (col & ~1) * 2;
    const int ra = rowbase + (odd ? 2 : 0);
    const int rb = ra + 1;
    *(u32*)(atile + ((ra * 256 + cb) ^ ((ra & 7) << 4))) = wa;
    *(u32*)(atile + ((rb * 256 + cb) ^ ((rb & 7) << 4))) = wb;
}

__global__ __launch_bounds__(512, 2) void fused_v8(const float* __restrict__ xyz,
                                                   const float* __restrict__ qbuf,
                                                   const u16* __restrict__ kb,
                                                   const u16* __restrict__ vb,
                                                   const int* __restrict__ knn_in,
                                                   const u16* __restrict__ wpack,
                                                   const float* __restrict__ pw1,
                                                   const float* __restrict__ pb1,
                                                   const float* __restrict__ pb2,
                                                   const float* __restrict__ ab1,
                                                   const float* __restrict__ ab2,
                                                   float* __restrict__ out) {
    __shared__ __align__(16) char atile[32768];   // [128][128] bf16 swizzled
    __shared__ float bias[3][D];                  // pb2, ab1, ab2
    __shared__ __align__(16) float diffs[128][4];
    __shared__ int nbrs[128];

    const int tid = threadIdx.x;
    if (tid < 128) bias[0][tid] = pb2[tid];
    else if (tid < 256) bias[1][tid - 128] = ab1[tid - 128];
    else if (tid < 384) bias[2][tid - 256] = ab2[tid - 256];

    const int wid = tid >> 6, lane = tid & 63;
    const int R = wid >> 2, c2 = wid & 3;
    const int c16 = lane & 15, grp = lane >> 4;
    const bool odd = (c16 & 1) != 0;

    // XCD-aware bijective swizzle for 512 blocks
    const int pid = (blockIdx.x & 7) * 64 + (blockIdx.x >> 3);

    // P2 hoisted pos-MLP-1 weights: 4 cols per thread (loop-invariant)
    const int cb4 = (tid & 31) * 4;   // column base
    const int rblk = tid >> 5;        // row block 0..15 (8 rows each)
    float w0a[4], w1a[4], w2a[4], ba[4];
#pragma unroll
    for (int c = 0; c < 4; ++c) {
        w0a[c] = pw1[cb4 + c];
        w1a[c] = pw1[D + cb4 + c];
        w2a[c] = pw1[2 * D + cb4 + c];
        ba[c]  = pb1[cb4 + c];
    }

    short8b wf[3][4][2];
#pragma unroll
    for (int m = 0; m < 3; ++m)
#pragma unroll
        for (int q = 0; q < 4; ++q)
#pragma unroll
            for (int ct = 0; ct < 2; ++ct)
                wf[m][q][ct] = *(const short8b*)(wpack + (size_t)m * 16384 +
                                                 (size_t)((q * 8 + c2 * 2 + ct) * 64 + lane) * 8);
    __syncthreads();

    for (int g = 0; g < 4; ++g) {
        const int p0 = pid * 32 + g * 8;
        __syncthreads();

        // P1: neighbor ids + pos diffs
        if (tid < 128) {
            const int pt = p0 + (tid >> 4);
            const int nb = knn_in[pt * KNN + (tid & 15)];
            nbrs[tid] = nb;
            diffs[tid][0] = xyz[pt * 3 + 0] - xyz[nb * 3 + 0];
            diffs[tid][1] = xyz[pt * 3 + 1] - xyz[nb * 3 + 1];
            diffs[tid][2] = xyz[pt * 3 + 2] - xyz[nb * 3 + 2];
        }
        __syncthreads();

        // P2: h1 = relu(pos_diff @ pw1 + pb1) -> atile
#pragma unroll
        for (int rr = 0; rr < 8; ++rr) {
            const int row = rblk * 8 + rr;
            const float4 dv = *(const float4*)&diffs[row][0];
            float h[4];
#pragma unroll
            for (int c = 0; c < 4; ++c) {
                float t = ba[c];
                t = fmaf(dv.x, w0a[c], t);
                t = fmaf(dv.y, w1a[c], t);
                t = fmaf(dv.z, w2a[c], t);
                h[c] = fmaxf(t, 0.f);
            }
            const u32 lo = cvtpk(h[0], h[1]);
            const u32 hi = cvtpk(h[2], h[3]);
            const u64 pk = (u64)lo | ((u64)hi << 32);
            const int byte = (row * 256 + cb4 * 2) ^ ((row & 7) << 4);
            *(u64*)(atile + byte) = pk;
        }
        __syncthreads();

        // P3: delta = h1 @ pw2 + pb2
        f32x4 del[4][2];
        gemm_reg(atile, wf[0], bias[0], R, c2, lane, del);
        __syncthreads();

        // P4: attn_in = q - k_g + delta -> atile
#pragma unroll
        for (int mt = 0; mt < 4; ++mt) {
            const int pt = p0 + R * 4 + mt;
            const int rowbase = R * 64 + mt * 16 + grp * 4;
#pragma unroll
            for (int ct = 0; ct < 2; ++ct) {
                const int col = c2 * 32 + ct * 16 + c16;
                const float qv = qbuf[(size_t)pt * D + col];
                float v[4];
#pragma unroll
                for (int r = 0; r < 4; ++r) {
                    const float kg = bf2f(kb[(size_t)nbrs[rowbase + r] * D + col]);
                    v[r] = qv - kg + del[mt][ct][r];
                }
                pair_store(atile, rowbase, col, odd, v[0], v[1], v[2], v[3]);
            }
        }
        __syncthreads();

        // P5: h2 = relu(attn_in @ aw1 + ab1)
        f32x4 acc[4][2];
        gemm_reg(atile, wf[1], bias[1], R, c2, lane, acc);
        __syncthreads();

        // P6: store relu(h2) -> atile
#pragma unroll
        for (int mt = 0; mt < 4; ++mt) {
            const int rowbase = R * 64 + mt * 16 + grp * 4;
#pragma unroll
            for (int ct = 0; ct < 2; ++ct) {
                const int col = c2 * 32 + ct * 16 + c16;
                pair_store(atile, rowbase, col, odd,
                           fmaxf(acc[mt][ct][0], 0.f), fmaxf(acc[mt][ct][1], 0.f),
                           fmaxf(acc[mt][ct][2], 0.f), fmaxf(acc[mt][ct][3], 0.f));
            }
        }
        __syncthreads();

        // P7: logits = h2 @ aw2 + ab2
        gemm_reg(atile, wf[2], bias[2], R, c2, lane, acc);

        // P8: softmax + weighted sum; predicated out-write
#pragma unroll
        for (int mt = 0; mt < 4; ++mt) {
            const int pt = p0 + R * 4 + mt;
            const int rowbase = R * 64 + mt * 16 + grp * 4;
#pragma unroll
            for (int ct = 0; ct < 2; ++ct) {
                const int col = c2 * 32 + ct * 16 + c16;
                float vg[4];
#pragma unroll
                for (int r = 0; r < 4; ++r)
                    vg[r] = bf2f(vb[(size_t)nbrs[rowbase + r] * D + col]);
                float m = fmaxf(fmaxf(acc[mt][ct][0], acc[mt][ct][1]),
                                fmaxf(acc[mt][ct][2], acc[mt][ct][3]));
                m = fmaxf(m, __shfl_xor(m, 16));
                m = fmaxf(m, __shfl_xor(m, 32));
                float e[4], s = 0.f;
#pragma unroll
                for (int r = 0; r < 4; ++r) { e[r] = __expf(acc[mt][ct][r] - m); s += e[r]; }
                s += __shfl_xor(s, 16);
                s += __shfl_xor(s, 32);
                const float inv = 1.f / s;
                float o = 0.f;
#pragma unroll
                for (int r = 0; r < 4; ++r) o = fmaf(e[r] * inv, vg[r] + del[mt][ct][r], o);
                o += __shfl_xor(o, 16);
                o += __shfl_xor(o, 32);
                if (grp == mt) out[(size_t)pt * D + col] = o;
            }
        }
    }
}

// ---------------------------------------------------------------------------
extern "C" void kernel_launch(void* const* d_in, const int* in_sizes, int n_in,
                              void* d_out, int out_size, void* d_ws, size_t ws_size,
                              hipStream_t stream) {
    const float* xyz = (const float*)d_in[0];
    const float* feat = (const float*)d_in[1];
    const float* wq = (const float*)d_in[2];
    const float* bq = (const float*)d_in[3];
    const float* wk = (const float*)d_in[4];
    const float* bk = (const float*)d_in[5];
    const float* wv = (const float*)d_in[6];
    const float* bv = (const float*)d_in[7];
    const float* pw1 = (const float*)d_in[8];
    const float* pb1 = (const float*)d_in[9];
    const float* pw2 = (const float*)d_in[10];
    const float* pb2 = (const float*)d_in[11];
    const float* aw1 = (const float*)d_in[12];
    const float* ab1 = (const float*)d_in[13];
    const float* aw2 = (const float*)d_in[14];
    const float* ab2 = (const float*)d_in[15];

    float* ws = (float*)d_ws;
    // --- knn phase ---
    float* dcomp = ws;                              // 16*20*16384 = 5,242,880 f32
    float* pmins = ws;                              // overlays: 256*16384 f32
    u16* jcomp = (u16*)(ws + 5242880);              // 5,242,880 u16
    float* thr = ws + 8126464;                      // 16,384 f32
    int* knn = (int*)(ws + 8142848);                // 262,144 i32
    // --- mlp phase (overlays dcomp region, dead after merge) ---
    float* qbuf = ws;                               // 2,097,152 f32
    u16* kb = (u16*)(ws + 2097152);                 // 2,097,152 u16
    u16* vb = (u16*)(ws + 3145728);                 // 2,097,152 u16
    u16* wpack = (u16*)(ws + 4194304);              // 49,152 u16
    float* out = (float*)d_out;

    hipLaunchKernelGGL(knn_minslots, dim3(128, NCH_M), dim3(128), 0, stream, xyz, pmins);
    hipLaunchKernelGGL(knn_thresh, dim3(64), dim3(256), 0, stream, pmins, thr);
    hipLaunchKernelGGL(knn_select, dim3(128, NCH_S), dim3(128), 0, stream,
                       xyz, thr, dcomp, jcomp);
    hipLaunchKernelGGL(knn_merge, dim3(256), dim3(64), 0, stream, dcomp, jcomp, knn);
    hipLaunchKernelGGL(qkv_pack, dim3(704), dim3(256), 0, stream,
                       feat, wq, bq, wk, bk, wv, bv, pw2, aw1, aw2,
                       qbuf, kb, vb, wpack);
    hipLaunchKernelGGL(fused_v8, dim3(512), dim3(512), 0, stream,
                       xyz, qbuf, kb, vb, knn, wpack,
                       pw1, pb1, pb2, ab1, ab2, out);
}